// Round 6
// baseline (101.898 us; speedup 1.0000x reference)
//
#include <hip/hip_runtime.h>

// VQVAE quantize.  x: [8,64,32,32] fp32, codebook: [8192,64] fp32.
// d_out (fp32, concat): [0,524288) quant_out | [524288] commit_loss |
//                       [524289] codebook_loss | [524290,532482) indices
//
// argmin via fp16x2 emulated-fp32 MFMA GEMM (3 terms):
//   v = h + m (2 fp16, exact to ~|v|*2^-23); dot ~= hh + hm + mh
//   score = dot - 0.5*e2[k]  (argmax score == argmin d2; absmax 0 R12-R23)
//
// R23 post-mortem: argmin off the top-5 (<41.2us, est 36-40); totals
// across R19-R23 fit dur = C + argmin with C ~= 58-62us of non-argmin
// time (poison fill 41us? + prep ~10 at 32 blocks + gather + final +
// 3 launch gaps). R24 attacks C, argmin UNTOUCHED (attribution):
//  (1) prep: 256 blocks x 256 thr, 1 thread per (row,octet), e2 via
//      shfl_xor over the 8-lane row group -> ~2-3us.
//  (2) final merged into gather (last-block ticket, fence discipline
//      per rocPRIM pattern; same 1024 partials, same reduce order ->
//      bitwise-identical losses). prep zeroes the ticket each launch.
//  (3) 4 kernels -> 3 (one launch gap removed).
// R22 lesson: combined VGPR+AGPR budget caps waves/SIMD (unified file).
// R21 lesson: chunk loop stays rolled. R13: 4-tile tl clusters only.

#define N_PTS   8192
#define K_CODES 8192
#define C_DIM   64
#define HWSZ    1024
#define QOUT_N  524288
#define SPLITS  32            // codes per split = 256 = 4 chunks of 64
#define NCH     4             // chunks per split

// ---- workspace layout (bytes) ----
#define WS_PACK  0            // u64 [32][8192]       = 2097152
#define WS_CBS   2097152      // u16 [2*8][8192][8]   = 2097152
#define WS_E2H   4194304      // float [8192]         = 32768
#define WS_PART  4227072      // float [1024]         = 4096
#define WS_TICK  4231168      // int                  = 4

typedef __attribute__((ext_vector_type(8))) short    short8;
typedef __attribute__((ext_vector_type(8))) _Float16 half8;
typedef __attribute__((ext_vector_type(4))) float    floatx4;

__device__ __forceinline__ half8 as_h8(short8 v) {
    return __builtin_bit_cast(half8, v);
}
__device__ __forceinline__ void split2(float v, unsigned short& h,
                                       unsigned short& m) {
    _Float16 hh = (_Float16)v;                     // RNE
    float r = v - (float)hh;
    _Float16 mm = (_Float16)r;
    h = __builtin_bit_cast(unsigned short, hh);
    m = __builtin_bit_cast(unsigned short, mm);
}

// ============================================================
// Kernel A: prep — codebook split + e2. 256 blocks x 256 thr,
// one thread per (code row k, channel octet g): loads 32B
// contiguous (perfectly coalesced per wave), split2 x8, two
// 16B plane writes; e2[k] via shfl_xor over the 8 g-lanes of
// the row (lanes k*8+g are wave-contiguous). Also zeroes the
// gather ticket for this launch.
// Plane layout [p*8+g][k][8], p in {0=h,1=m}: 16B per
// (code, c-octet g) == one MFMA fragment k-group.
// ============================================================
__global__ __launch_bounds__(256)
void vq_prep_kernel(const float* __restrict__ cb,
                    unsigned short* __restrict__ cbS,
                    float* __restrict__ e2h,
                    int* __restrict__ ticket)
{
    const int gt = blockIdx.x * 256 + threadIdx.x;   // 0..65535
    const int k  = gt >> 3;
    const int g  = gt & 7;
    if (gt == 0) *ticket = 0;

    const float* rp = cb + (size_t)k * C_DIM + g * 8;
    float4 a = *(const float4*)(rp);
    float4 b = *(const float4*)(rp + 4);
    float vv[8] = {a.x, a.y, a.z, a.w, b.x, b.y, b.z, b.w};
    unsigned short h8[8], m8[8];
    float s = 0.0f;
    #pragma unroll
    for (int j = 0; j < 8; ++j) {
        s = fmaf(vv[j], vv[j], s);
        split2(vv[j], h8[j], m8[j]);
    }
    *(uint4*)(cbS + ((size_t)(0 * 8 + g) * 8192 + k) * 8) = *(const uint4*)h8;
    *(uint4*)(cbS + ((size_t)(1 * 8 + g) * 8192 + k) * 8) = *(const uint4*)m8;

    #pragma unroll
    for (int msk = 1; msk < 8; msk <<= 1) s += __shfl_xor(s, msk, 64);
    if (g == 0) e2h[k] = 0.5f * s;
}

// ============================================================
// Kernel B: argmin via 16x16x32 f16 MFMA. grid (64 m-blocks,
// 32 splits) = 2048 blocks x 256 threads (4 waves). Wave owns
// 32 points (2 tiles of 16) x 256 codes. NO LDS, NO barriers:
// per 16-code tile, bf[2][2] (4x dwordx4) and e2 are read
// straight from global (16KB chunk is L1-resident; co-resident
// blocks share the split). A-frags from x in regs (~32 regs).
// Combined reg state ~100 -> with launch_bounds(256,4) at least
// 4 waves/SIMD co-resident. UNCHANGED from R23.
// Final reduce via __shfl_xor u64 min (8 owner cols).
// Layouts (verified m89/m91/m120): A[m=lane&15][k=quad*8+j],
// B[k=quad*8+j][n=lane&15], C: col=lane&15, row=quad*4+reg.
// ============================================================
__global__ __launch_bounds__(256, 4)
void vq_argmin_kernel(const float* __restrict__ x,
                      const unsigned short* __restrict__ cbS,
                      const float* __restrict__ e2h,
                      unsigned long long* __restrict__ packedS)
{
    const int tid   = threadIdx.x;       // 0..255
    const int lane  = tid & 63;
    const int w     = tid >> 6;          // 0..3
    const int col   = lane & 15;
    const int quad  = lane >> 4;
    const int mb    = blockIdx.x;        // 0..63
    const int split = blockIdx.y;        // 0..31
    const int m0    = mb * 128 + w * 32;
    const int nb0   = split * 256;

    // A fragments straight from x: pt = m0 + t*16 + col, channel
    // c = s*32 + quad*8 + j (matches MFMA k = quad*8+j per s-step).
    // 128 pts per block never cross an image (1024 pts/image).
    const int bimg = m0 >> 10;
    const int hw0  = m0 & 1023;
    const float* xb = x + (size_t)bimg * (C_DIM * HWSZ);
    half8 af[2][2][2];                   // [tile][plane][s] = 32 regs
    #pragma unroll
    for (int t = 0; t < 2; ++t) {
        const int hw = hw0 + t * 16 + col;
        #pragma unroll
        for (int s = 0; s < 2; ++s) {
            unsigned short h8[8], m8[8];
            #pragma unroll
            for (int j = 0; j < 8; ++j) {
                float v = xb[(size_t)(s * 32 + quad * 8 + j) * HWSZ + hw];
                split2(v, h8[j], m8[j]);
            }
            af[t][0][s] = as_h8(*(const short8*)h8);
            af[t][1][s] = as_h8(*(const short8*)m8);
        }
    }

    float bestv[2][4];
    int   besti[2][4];
    #pragma unroll
    for (int t = 0; t < 2; ++t)
        #pragma unroll
        for (int r = 0; r < 4; ++r) {
            bestv[t][r] = __uint_as_float(0xFF800000u);  // -inf
            besti[t][r] = 0;
        }

    // main loop: 4 chunks x 4 tiles of 16 codes; everything from
    // global (L1). Rolled ch loop (R21: unroll -> spill); tl loop
    // unrolled so the compiler pipelines loads across tiles.
    #pragma clang loop unroll(disable)
    for (int ch = 0; ch < NCH; ++ch) {
        const int k0 = nb0 + ch * 64;
        #pragma unroll
        for (int tl = 0; tl < 4; ++tl) {
            const int code = k0 + tl * 16 + col;
            half8 bf[2][2];
            #pragma unroll
            for (int p = 0; p < 2; ++p)
                #pragma unroll
                for (int s = 0; s < 2; ++s) {
                    int seg = p * 8 + s * 4 + quad;
                    bf[p][s] = as_h8(*(const short8*)(cbS + ((size_t)seg * 8192 + code) * 8));
                }
            float me2 = -e2h[code];

            floatx4 acc[2];
            #pragma unroll
            for (int t = 0; t < 2; ++t) acc[t] = (floatx4){me2, me2, me2, me2};

            #pragma unroll
            for (int s = 0; s < 2; ++s) {
                #pragma unroll
                for (int t = 0; t < 2; ++t)
                    acc[t] = __builtin_amdgcn_mfma_f32_16x16x32_f16(af[t][0][s], bf[0][s], acc[t], 0, 0, 0); // hh
                #pragma unroll
                for (int t = 0; t < 2; ++t)
                    acc[t] = __builtin_amdgcn_mfma_f32_16x16x32_f16(af[t][0][s], bf[1][s], acc[t], 0, 0, 0); // hm
                #pragma unroll
                for (int t = 0; t < 2; ++t)
                    acc[t] = __builtin_amdgcn_mfma_f32_16x16x32_f16(af[t][1][s], bf[0][s], acc[t], 0, 0, 0); // mh
            }

            #pragma unroll
            for (int t = 0; t < 2; ++t)
                #pragma unroll
                for (int r = 0; r < 4; ++r) {
                    float sc = acc[t][r];
                    bool gt = sc > bestv[t][r];    // strict: earlier code wins
                    bestv[t][r] = gt ? sc   : bestv[t][r];
                    besti[t][r] = gt ? code : besti[t][r];
                }
        }
    }

    // final reduce over the 16 col-candidates per point, in-register:
    // per (t,r), u64-min across the 16 col lanes of each quad group
    // (xor masks 1,2,4,8 stay within the group). Lane with col==t*4+r
    // (col 0..7) owns pair (t,r) and writes point m0+t*16+quad*4+r.
    unsigned long long own = 0;
    #pragma unroll
    for (int t = 0; t < 2; ++t)
        #pragma unroll
        for (int r = 0; r < 4; ++r) {
            unsigned u = __float_as_uint(-bestv[t][r]);   // key ascending
            u = ((int)u < 0) ? ~u : (u | 0x80000000u);
            unsigned long long p = ((unsigned long long)u << 32) | (unsigned)besti[t][r];
            #pragma unroll
            for (int msk = 1; msk < 16; msk <<= 1) {
                unsigned long long q = __shfl_xor(p, msk, 64);
                p = (q < p) ? q : p;
            }
            own = (col == t * 4 + r) ? p : own;
        }
    if (col < 8) {
        const int mpt = m0 + (col >> 2) * 16 + quad * 4 + (col & 3);
        packedS[(size_t)split * N_PTS + mpt] = own;
    }
}

// ============================================================
// Kernel C: gather + final. 256 blocks x 256; block owns 32
// points, 8 threads/point. Phase 1: thread (p=tid&31, sg=tid>>5)
// reduces split slots {sg*4..sg*4+3} -> sred[8][32]. Phase 2:
// every thread combines the 8 partials. Phase 3: thread handles
// channels sg*8..sg*8+7, fully coalesced; per-wave loss partials.
// Phase 4 (last-block ticket): the 256th block to finish re-reads
// the 1024 partials and reduces them EXACTLY as the old final
// kernel did (same order -> bitwise-identical losses). Fence
// discipline: stores -> __syncthreads -> tid0 __threadfence +
// atomicAdd (release); last block: __threadfence (acquire) ->
// plain loads (rocPRIM last-block pattern, device scope).
// ============================================================
__global__ __launch_bounds__(256)
void vq_gather_kernel(const float* __restrict__ x,
                      const float* __restrict__ cb,
                      const unsigned long long* __restrict__ packedS,
                      float* __restrict__ out,
                      float* __restrict__ part,
                      int* __restrict__ ticket)
{
    __shared__ unsigned long long sred[8][32];
    __shared__ float wloss[4];
    __shared__ int lastFlag;
    const int tid = threadIdx.x;
    const int p   = tid & 31;
    const int sg  = tid >> 5;           // 0..7
    const int n0  = blockIdx.x * 32;
    const int n   = n0 + p;

    {
        unsigned long long v = packedS[(size_t)(sg * 4) * N_PTS + n];
        #pragma unroll
        for (int j = 1; j < 4; ++j) {
            unsigned long long q = packedS[(size_t)(sg * 4 + j) * N_PTS + n];
            v = (q < v) ? q : v;
        }
        sred[sg][p] = v;
    }
    __syncthreads();

    unsigned long long v = sred[0][p];
    #pragma unroll
    for (int s = 1; s < 8; ++s) {
        unsigned long long q = sred[s][p];
        v = (q < v) ? q : v;
    }
    const int idx = (int)(v & 0xFFFFFFFFull);
    if (tid < 32) out[QOUT_N + 2 + n0 + tid] = (float)idx;

    const int c0  = sg * 8;
    const int b   = n >> 10;
    const int hw  = n & 1023;
    const float* xb = x   + (size_t)b * (C_DIM * HWSZ) + hw;
    float*       ob = out + (size_t)b * (C_DIM * HWSZ) + hw;

    float s = 0.0f;
    #pragma unroll
    for (int c4 = 0; c4 < 2; ++c4) {
        float4 q = *(const float4*)(cb + (size_t)idx * C_DIM + c0 + c4 * 4);
        float qa[4] = {q.x, q.y, q.z, q.w};
        #pragma unroll
        for (int j = 0; j < 4; ++j) {
            int c = c0 + c4 * 4 + j;
            float xv = xb[c * HWSZ];
            float d  = qa[j] - xv;          // quant - x (reference rounding)
            s = fmaf(d, d, s);
            ob[c * HWSZ] = xv + d;          // straight-through: x + (q - x)
        }
    }

    #pragma unroll
    for (int off = 32; off > 0; off >>= 1) s += __shfl_down(s, off, 64);
    if ((tid & 63) == 0) part[blockIdx.x * 4 + (tid >> 6)] = s;

    // ---- last-block final reduce (replaces kernel D) ----
    __syncthreads();                     // partials ordered before ticket
    if (tid == 0) {
        __threadfence();                 // release partials, device scope
        int prev = atomicAdd(ticket, 1);
        lastFlag = (prev == 255);
    }
    __syncthreads();
    if (lastFlag) {
        __threadfence();                 // acquire all blocks' partials
        float s2 = part[tid] + part[tid + 256]
                 + part[tid + 512] + part[tid + 768];
        #pragma unroll
        for (int off = 32; off > 0; off >>= 1) s2 += __shfl_down(s2, off, 64);
        if ((tid & 63) == 0) wloss[tid >> 6] = s2;
        __syncthreads();
        if (tid == 0) {
            float m = (wloss[0] + wloss[1] + wloss[2] + wloss[3])
                    * (1.0f / (float)QOUT_N);
            out[QOUT_N]     = m;   // commitment_loss
            out[QOUT_N + 1] = m;   // codebook_loss
        }
    }
}

extern "C" void kernel_launch(void* const* d_in, const int* in_sizes, int n_in,
                              void* d_out, int out_size, void* d_ws, size_t ws_size,
                              hipStream_t stream)
{
    const float* x  = (const float*)d_in[0];   // [8,64,32,32]
    const float* cb = (const float*)d_in[1];   // [8192,64]
    float* out = (float*)d_out;
    char*  ws  = (char*)d_ws;
    (void)ws_size;

    unsigned long long* packedS = (unsigned long long*)(ws + WS_PACK);
    unsigned short* cbS = (unsigned short*)(ws + WS_CBS);
    float* e2h = (float*)(ws + WS_E2H);
    float* part = (float*)(ws + WS_PART);
    int* ticket = (int*)(ws + WS_TICK);

    vq_prep_kernel<<<256, 256, 0, stream>>>(cb, cbS, e2h, ticket);
    vq_argmin_kernel<<<dim3(64, SPLITS), 256, 0, stream>>>(x, cbS, e2h, packedS);
    vq_gather_kernel<<<256, 256, 0, stream>>>(x, cb, packedS, out, part, ticket);
}